// Round 4
// baseline (65.829 us; speedup 1.0000x reference)
//
#include <hip/hip_runtime.h>

#define BATCH 1024
#define NEG 64
#define KNB 128
#define FD 128
#define NV 200

// workspace layout (float offsets); every slot below is written every launch,
// so no zero-init pass is needed (re-poison safe).
#define O_INF  0                                   // [NV][BATCH] per-block pi
#define O_EMB  (NV * BATCH)                        // [NV][BATCH] per-block e
#define O_TW   (2 * NV * BATCH)                    // [NV][BATCH] per-block tw
#define O_LOSS (3 * NV * BATCH)                    // [BATCH]     per-block row-loss
#define O_NF   (3 * NV * BATCH + BATCH)            // [NV][NEG]   neg pi
#define O_FW   (3 * NV * BATCH + BATCH + NV * NEG) // [NV][NEG]   neg false_w
#define O_CELL (3 * NV * BATCH + BATCH + 2 * NV * NEG)
// cells: [0..3] dot accumulators (d2,d4,d6,d8), [4] loss accum, [5] counter(uint)

__device__ __forceinline__ float log_sig(float x) {
    // log(sigmoid(x) + 0.001); saturates correctly at both ends
    float s = 1.0f / (1.0f + expf(-x));
    return logf(s + 0.001f);
}

// ---- fused main kernel ----
// 512 threads = 8 waves; __launch_bounds__(512,8) keeps VGPR<=64 -> 32 waves/CU.
// f32 gather (A/B rounds 1-3 showed: the random-row gather is fabric-throughput
// bound ~4.5 TB/s; bf16 table loses once rebuild traffic is counted, extra MLP
// is a null). This round removes everything around the gather: no atomics for
// the column sums (per-block column-major slabs), no memset, dense W phase
// split so per-thread load chain is 64 not 128.
__global__ __launch_bounds__(512, 8) void fused_kernel(
    const int* __restrict__ ti, const int* __restrict__ tl, const int* __restrict__ ns,
    const int* __restrict__ rpr_arg, const float* __restrict__ rpr_mat,
    const float* __restrict__ feat, const float* __restrict__ W,
    const float* __restrict__ emb, const float* __restrict__ nce,
    float* __restrict__ ws)
{
    int b = blockIdx.x, t = threadIdx.x, lane = t & 63, w = t >> 6;
    bool pair = (b < BATCH);

    // zero final's accumulator cells; fused strictly precedes final in stream
    // order, and redundant zero-writes from many blocks are benign.
    if (t < 6) ws[O_CELL + t] = 0.f;

    __shared__ int   nbr_sh[256];
    __shared__ float w_sh[256];
    __shared__ float part[8][FD];      // per-wave gather partials
    __shared__ float agg_i[FD], agg_l[FD];
    __shared__ float pB[NV], lB[NV];   // dense-phase group-B halves
    __shared__ float red[4][4];

    if (pair) {
        if (t < 256) {
            int idx = (t < 128) ? ti[b] : tl[b];      // wave-uniform scalar load
            nbr_sh[t] = rpr_arg[(size_t)idx * KNB + (t & 127)];
            w_sh[t]   = rpr_mat[(size_t)idx * KNB + (t & 127)];
        }
    } else if (t < 128) {
        int idx = ns[b - BATCH];
        nbr_sh[t] = rpr_arg[(size_t)idx * KNB + t];
        w_sh[t]   = rpr_mat[(size_t)idx * KNB + t];
    }
    __syncthreads();

    // gather: one float2/lane = one full 512B f32 row per wave-instruction;
    // 8 rows in flight per batch; pure VGPR FMA accumulate.
    float accX = 0.f, accY = 0.f;
    {
        // pair: wave w covers nbr rows [32w,32w+32): waves 0-3 inf, 4-7 lf
        // neg:  wave w covers nbr rows [16w,16w+16)
        int nb   = pair ? 4 : 2;                  // batches of 8 rows
        int base = pair ? (w * 32) : (w * 16);
        for (int bb = 0; bb < nb; ++bb) {
            int k0 = base + bb * 8;
            float2 d[8]; float ww[8];
            #pragma unroll
            for (int j = 0; j < 8; ++j) {
                ww[j] = w_sh[k0 + j];
                d[j]  = *(const float2*)&feat[(size_t)(unsigned)nbr_sh[k0 + j] * FD + 2 * lane];
            }
            #pragma unroll
            for (int j = 0; j < 8; ++j) {
                accX += ww[j] * d[j].x;
                accY += ww[j] * d[j].y;
            }
        }
    }
    ((float2*)part[w])[lane] = make_float2(accX, accY);   // cols 2*lane, 2*lane+1
    __syncthreads();

    if (pair) {
        if (t < FD)
            agg_i[t] = part[0][t] + part[1][t] + part[2][t] + part[3][t];
        else if (t < 2 * FD) {
            int u = t - FD;
            agg_l[u] = part[4][u] + part[5][u] + part[6][u] + part[7][u];
        }
    } else if (t < FD) {
        float s = 0.f;
        #pragma unroll
        for (int p = 0; p < 8; ++p) s += part[p][t];
        agg_i[t] = s;
    }
    __syncthreads();

    // dense [128]x[128,200] + relu, f-split across two thread groups:
    // group 0 = threads [0,NV) does f in [0,64); group 1 = [256,256+NV) does
    // f in [64,128). Per-thread W-load chain halves vs the single-group loop.
    int g  = (t < NV) ? 0 : ((t >= 256 && t < 256 + NV) ? 1 : -1);
    int tc = (g == 1) ? t - 256 : t;
    float piH = 0.f, plH = 0.f;
    if (g >= 0) {
        int f0 = g * 64;
        #pragma unroll 8
        for (int f = f0; f < f0 + 64; ++f) {
            float wv = W[f * NV + tc];
            piH += agg_i[f] * wv;
            if (pair) plH += agg_l[f] * wv;
        }
    }
    if (g == 1) { pB[tc] = piH; lB[tc] = plH; }
    __syncthreads();

    float pi = 0.f, pl = 0.f;
    if (g == 0) {
        pi = fmaxf(piH + pB[t], 0.f);
        pl = fmaxf(plH + lB[t], 0.f);   // zero/unused for neg blocks
    }

    if (pair) {
        float e = 0.f, tw = 0.f;
        if (g == 0) {
            e  = emb[(size_t)ti[b] * NV + t];
            tw = nce[(size_t)tl[b] * NV + t];
            // column-major per-block slabs: contiguous per-column for final
            ws[O_INF + (size_t)t * BATCH + b] = pi;
            ws[O_EMB + (size_t)t * BATCH + b] = e;
            ws[O_TW  + (size_t)t * BATCH + b] = tw;
        }
        if (t < 256) {     // waves 0-3 hold all nonzero dot terms
            float v0 = pi * pl;   // p1
            float v1 = e * tw;    // p3
            float v2 = e * pl;    // p5
            float v3 = tw * pi;   // p7
            #pragma unroll
            for (int o = 32; o > 0; o >>= 1) {
                v0 += __shfl_down(v0, o, 64);
                v1 += __shfl_down(v1, o, 64);
                v2 += __shfl_down(v2, o, 64);
                v3 += __shfl_down(v3, o, 64);
            }
            if (lane == 0) {
                red[0][w] = v0; red[1][w] = v1; red[2][w] = v2; red[3][w] = v3;
            }
        }
        __syncthreads();
        if (t == 0) {
            float d1 = red[0][0] + red[0][1] + red[0][2] + red[0][3];
            float d3 = red[1][0] + red[1][1] + red[1][2] + red[1][3];
            float d5 = red[2][0] + red[2][1] + red[2][2] + red[2][3];
            float d7 = red[3][0] + red[3][1] + red[3][2] + red[3][3];
            ws[O_LOSS + b] = 1.5f * log_sig(d1) + 0.75f * log_sig(d3)
                           + 1.5f * log_sig(d5) + 1.5f * log_sig(d7);
        }
    } else if (g == 0) {
        int nb_ = b - BATCH;
        ws[O_NF + (size_t)t * NEG + nb_] = pi;
        ws[O_FW + (size_t)t * NEG + nb_] = nce[(size_t)ns[nb_] * NV + t];
    }
}

// ---------------- per-column reduce + dots + loss (last-block finishes) ----------
// 200 blocks: block t reduces column t of all slabs (contiguous, coalesced),
// contributes its 4 dot products + loss partial via 5 scalar atomics; the last
// block to arrive computes the final output. No third kernel launch.
__global__ __launch_bounds__(256) void final_kernel(
    float* __restrict__ ws, float* __restrict__ out)
{
    int t = blockIdx.x, tid = threadIdx.x, lane = tid & 63, w = tid >> 6;
    const float* Ai = ws + O_INF + (size_t)t * BATCH;
    const float* Ae = ws + O_EMB + (size_t)t * BATCH;
    const float* At = ws + O_TW  + (size_t)t * BATCH;
    float si = 0.f, se = 0.f, st = 0.f;
    for (int i = tid; i < BATCH; i += 256) { si += Ai[i]; se += Ae[i]; st += At[i]; }
    float sn = 0.f, sf = 0.f;
    if (tid < NEG) {
        sn = ws[O_NF + t * NEG + tid];
        sf = ws[O_FW + t * NEG + tid];
    }
    float lp = 0.f;
    if (tid < 6) {                      // loss entries j with j % NV == t
        int j = t + NV * tid;
        if (j < BATCH) lp = ws[O_LOSS + j];
    }

    __shared__ float red[6][4];
    #pragma unroll
    for (int o = 32; o > 0; o >>= 1) {
        si += __shfl_down(si, o, 64); se += __shfl_down(se, o, 64);
        st += __shfl_down(st, o, 64); sn += __shfl_down(sn, o, 64);
        sf += __shfl_down(sf, o, 64); lp += __shfl_down(lp, o, 64);
    }
    if (lane == 0) {
        red[0][w] = si; red[1][w] = se; red[2][w] = st;
        red[3][w] = sn; red[4][w] = sf; red[5][w] = lp;
    }
    __syncthreads();
    if (tid == 0) {
        float Si = 0.f, Se = 0.f, St = 0.f, Sn = 0.f, Sf = 0.f, Lp = 0.f;
        #pragma unroll
        for (int i = 0; i < 4; ++i) {
            Si += red[0][i]; Se += red[1][i]; St += red[2][i];
            Sn += red[3][i]; Sf += red[4][i]; Lp += red[5][i];
        }
        float* c = ws + O_CELL;
        atomicAdd(&c[0], Si * Sn);   // -> d2 = sum(inf @ nf.T)
        atomicAdd(&c[1], Se * Sf);   // -> d4
        atomicAdd(&c[2], Se * Sn);   // -> d6
        atomicAdd(&c[3], St * Sn);   // -> d8
        atomicAdd(&c[4], Lp);        // per-row loss accumulation
        __threadfence();
        unsigned old = atomicAdd((unsigned*)&c[5], 1u);
        if (old == NV - 1) {         // last column-block finishes the loss
            float d2 = atomicAdd(&c[0], 0.f);
            float d4 = atomicAdd(&c[1], 0.f);
            float d6 = atomicAdd(&c[2], 0.f);
            float d8 = atomicAdd(&c[3], 0.f);
            float lacc = atomicAdd(&c[4], 0.f);
            float total = lacc + (float)BATCH *
                (1.5f * log_sig(-d2) + 0.75f * log_sig(-d4)
               + 1.5f * log_sig(-d6) + 1.5f * log_sig(-d8));
            out[0] = -total / (float)BATCH;
        }
    }
}

extern "C" void kernel_launch(void* const* d_in, const int* in_sizes, int n_in,
                              void* d_out, int out_size, void* d_ws, size_t ws_size,
                              hipStream_t stream) {
    const int*   ti      = (const int*)d_in[0];
    const int*   tl      = (const int*)d_in[1];
    const int*   ns      = (const int*)d_in[2];
    const int*   rpr_arg = (const int*)d_in[3];
    const float* rpr_mat = (const float*)d_in[4];
    const float* feat    = (const float*)d_in[5];
    const float* emb     = (const float*)d_in[6];
    const float* nce     = (const float*)d_in[7];
    const float* W       = (const float*)d_in[8];

    float* ws = (float*)d_ws;   // ~2.56 MB used

    fused_kernel<<<BATCH + NEG, 512, 0, stream>>>(
        ti, tl, ns, rpr_arg, rpr_mat, feat, W, emb, nce, ws);
    final_kernel<<<NV, 256, 0, stream>>>(ws, (float*)d_out);
}